// Round 2
// baseline (1959.718 us; speedup 1.0000x reference)
//
#include <hip/hip_runtime.h>
#include <stdint.h>

// ---------------------------------------------------------------------------
// Decoder: GRU(seq) + attention + dense + vocab projection
// H=512, V=32000, B=16, Td=Te=64
// Round 2: persistent single-kernel GRU (weights in registers, flag-array
// grid barrier per step) replacing 64 sequential step launches.
// fp32 everywhere except logits GEMM (bf16 MFMA, fp32 accumulate).
// ---------------------------------------------------------------------------

#define Hdim 512
#define Vdim 32000
#define Bdim 16
#define Tdim 64
#define BT   1024   // B*Td rows
#define GRU_BLOCKS 128

typedef __attribute__((ext_vector_type(8))) short bf16x8;
typedef __attribute__((ext_vector_type(4))) float f32x4;

static __device__ __forceinline__ unsigned short f2bf(float f) {
    unsigned u = __float_as_uint(f);
    u = u + 0x7FFFu + ((u >> 16) & 1u);   // round-to-nearest-even
    return (unsigned short)(u >> 16);
}

// --------------------------- small utility kernels -------------------------

__global__ void zero_kernel(float* p, int n) {
    int i = blockIdx.x * 256 + threadIdx.x;
    if (i < n) p[i] = 0.f;
}

__global__ void f32_to_bf16_kernel(const float* __restrict__ in, unsigned short* __restrict__ out, int n) {
    int i = blockIdx.x * 256 + threadIdx.x;
    int stride = gridDim.x * 256;
    for (; i < n; i += stride) out[i] = f2bf(in[i]);
}

// --------------------------- generic fp32 GEMM -----------------------------
// C[M x N] = act( A(M x K, lda) @ B(N x K, ldb)^T + bias ), dims %64==0, K%16==0
// grid = (N/64, M/64), block = 256

__global__ __launch_bounds__(256) void gemm_f32(
    const float* __restrict__ A, int lda,
    const float* __restrict__ B, int ldb,
    const float* __restrict__ bias,
    float* __restrict__ C, int ldc,
    int K, int act)
{
    __shared__ float As[16][68];
    __shared__ float Bs[16][68];
    const int tid = threadIdx.x;
    const int tx = tid & 15, ty = tid >> 4;
    const int m0 = blockIdx.y * 64, n0 = blockIdx.x * 64;

    float acc[4][4];
#pragma unroll
    for (int i = 0; i < 4; ++i)
#pragma unroll
        for (int j = 0; j < 4; ++j) acc[i][j] = 0.f;

    const int r  = tid >> 2;        // 0..63
    const int kq = (tid & 3) * 4;   // 0,4,8,12

    for (int k0 = 0; k0 < K; k0 += 16) {
        float4 a4 = *(const float4*)(A + (size_t)(m0 + r) * lda + k0 + kq);
        float4 b4 = *(const float4*)(B + (size_t)(n0 + r) * ldb + k0 + kq);
        As[kq + 0][r] = a4.x; As[kq + 1][r] = a4.y; As[kq + 2][r] = a4.z; As[kq + 3][r] = a4.w;
        Bs[kq + 0][r] = b4.x; Bs[kq + 1][r] = b4.y; Bs[kq + 2][r] = b4.z; Bs[kq + 3][r] = b4.w;
        __syncthreads();
#pragma unroll
        for (int k = 0; k < 16; ++k) {
            float4 av = *(const float4*)(&As[k][ty * 4]);
            float4 bv = *(const float4*)(&Bs[k][tx * 4]);
            acc[0][0] += av.x * bv.x; acc[0][1] += av.x * bv.y; acc[0][2] += av.x * bv.z; acc[0][3] += av.x * bv.w;
            acc[1][0] += av.y * bv.x; acc[1][1] += av.y * bv.y; acc[1][2] += av.y * bv.z; acc[1][3] += av.y * bv.w;
            acc[2][0] += av.z * bv.x; acc[2][1] += av.z * bv.y; acc[2][2] += av.z * bv.z; acc[2][3] += av.z * bv.w;
            acc[3][0] += av.w * bv.x; acc[3][1] += av.w * bv.y; acc[3][2] += av.w * bv.z; acc[3][3] += av.w * bv.w;
        }
        __syncthreads();
    }

    const float4 bv4 = *(const float4*)(bias + n0 + tx * 4);
#pragma unroll
    for (int i = 0; i < 4; ++i) {
        int row = m0 + ty * 4 + i;
        float4 v;
        v.x = acc[i][0] + bv4.x; v.y = acc[i][1] + bv4.y;
        v.z = acc[i][2] + bv4.z; v.w = acc[i][3] + bv4.w;
        if (act == 1) { v.x = tanhf(v.x); v.y = tanhf(v.y); v.z = tanhf(v.z); v.w = tanhf(v.w); }
        *(float4*)(C + (size_t)row * ldc + n0 + tx * 4) = v;
    }
}

// --------------------------- persistent GRU --------------------------------
// 128 blocks x 256 threads, all co-resident. Block bid owns hidden units
// j0=bid*4 .. j0+3, i.e. W_hh rows {g*512 + j0+jj : g in 0..2, jj in 0..3}.
// Lane l holds w[12][8] for k-slice l*8..l*8+7 in registers (loaded once).
// Per step: read h from global (L2), FMA partials, butterfly-reduce across
// the wave, 16 lanes/wave compute gates for (4 j) x (4 b per wave), write
// h_next + cat, then flag-array grid barrier (agent-scope atomics).

__global__ __launch_bounds__(256) void gru_persistent(
    const float* __restrict__ xp,        // (1024,1536) rows = b*64+t
    const float* __restrict__ Whh,       // (1536,512)
    const float* __restrict__ bhh,       // (1536)
    const int*   __restrict__ lengths,   // (16)
    float* __restrict__ hbuf,            // (2,16,512); buf0 zero-initialized
    int*   __restrict__ flags,           // (128) zero-initialized
    float* __restrict__ cat,             // (1024,1024) write cols [0,512)
    float* __restrict__ h_last)          // (16,512)
{
    const int bid  = blockIdx.x;
    const int tid  = threadIdx.x;
    const int wave = tid >> 6, lane = tid & 63;
    const int j0 = bid * 4;
    const int k0 = lane * 8;

    // --- load W_hh slice into registers (once) ---
    float w[12][8];
#pragma unroll
    for (int g = 0; g < 3; ++g)
#pragma unroll
        for (int jj = 0; jj < 4; ++jj) {
            const float* src = Whh + (size_t)(g * 512 + j0 + jj) * Hdim + k0;
            float4 a = *(const float4*)src;
            float4 b = *(const float4*)(src + 4);
            int r = g * 4 + jj;
            w[r][0] = a.x; w[r][1] = a.y; w[r][2] = a.z; w[r][3] = a.w;
            w[r][4] = b.x; w[r][5] = b.y; w[r][6] = b.z; w[r][7] = b.w;
        }

    // gate-lane precomputation
    const int gjj = lane >> 2;        // 0..3 (valid when lane<16)
    const int gbi = lane & 3;
    const int gb  = wave * 4 + gbi;
    const int gj  = j0 + gjj;
    float bh_r = 0.f, bh_z = 0.f, bh_n = 0.f;
    int   len_b = 0;
    if (lane < 16) {
        bh_r = bhh[gj]; bh_z = bhh[512 + gj]; bh_n = bhh[1024 + gj];
        len_b = lengths[gb];
    }

    for (int t = 0; t < Tdim; ++t) {
        const float* hcur = hbuf + (t & 1) * (Bdim * Hdim);
        float*       hnxt = hbuf + ((t + 1) & 1) * (Bdim * Hdim);

        float p[12][4];
#pragma unroll
        for (int r = 0; r < 12; ++r)
#pragma unroll
            for (int bi = 0; bi < 4; ++bi) p[r][bi] = 0.f;

#pragma unroll
        for (int bi = 0; bi < 4; ++bi) {
            const int b = wave * 4 + bi;
            const float* hp = hcur + b * Hdim + k0;
            float4 h0 = *(const float4*)hp;
            float4 h1 = *(const float4*)(hp + 4);
            float hv[8] = {h0.x, h0.y, h0.z, h0.w, h1.x, h1.y, h1.z, h1.w};
#pragma unroll
            for (int r = 0; r < 12; ++r)
#pragma unroll
                for (int k = 0; k < 8; ++k)
                    p[r][bi] += w[r][k] * hv[k];
        }

        // butterfly reduce across 64 lanes
#pragma unroll
        for (int off = 1; off < 64; off <<= 1)
#pragma unroll
            for (int r = 0; r < 12; ++r)
#pragma unroll
                for (int bi = 0; bi < 4; ++bi)
                    p[r][bi] += __shfl_xor(p[r][bi], off);

        if (lane < 16) {
            float hr = p[0 + gjj][gbi] + bh_r;
            float hz = p[4 + gjj][gbi] + bh_z;
            float hn = p[8 + gjj][gbi] + bh_n;
            const float* xrow = xp + (size_t)(gb * Tdim + t) * 1536;
            float xr = xrow[gj], xz = xrow[512 + gj], xn = xrow[1024 + gj];
            float rg = 1.f / (1.f + __expf(-(xr + hr)));
            float zg = 1.f / (1.f + __expf(-(xz + hz)));
            float ng = tanhf(xn + rg * hn);
            float hold = hcur[gb * Hdim + gj];
            float hnew = (1.f - zg) * ng + zg * hold;
            bool valid = t < len_b;
            float hkeep = valid ? hnew : hold;
            hnxt[gb * Hdim + gj] = hkeep;
            cat[(size_t)(gb * Tdim + t) * 1024 + gj] = valid ? hnew : 0.f;
            if (t == Tdim - 1) h_last[gb * Hdim + gj] = hkeep;
        }

        // ---- grid barrier (skip after last step) ----
        if (t == Tdim - 1) break;
        __threadfence();
        __syncthreads();
        if (tid == 0)
            __hip_atomic_store(&flags[bid], t + 1, __ATOMIC_RELEASE, __HIP_MEMORY_SCOPE_AGENT);
        if (tid < GRU_BLOCKS) {
            while (__hip_atomic_load(&flags[tid], __ATOMIC_ACQUIRE, __HIP_MEMORY_SCOPE_AGENT) <= t)
                __builtin_amdgcn_s_sleep(1);
        }
        __syncthreads();
    }
}

// ------------------------------ attention ----------------------------------
// one block per (b,d); energies -> softmax over valid e -> context
// writes cat[:, 512:1024]

__global__ __launch_bounds__(256) void attn_kernel(
    const float* __restrict__ encp,     // (1024,512)
    const float* __restrict__ decp,     // (1024,512)
    const float* __restrict__ enc,      // (16,64,512)
    const float* __restrict__ battn,    // (512)
    const float* __restrict__ vw,       // (512)
    const float* __restrict__ vb,       // (1)
    const int* __restrict__ enc_len,    // (16)
    const int* __restrict__ dec_len,    // (16)
    float* __restrict__ cat)            // (1024,1024)
{
    const int blk = blockIdx.x;
    const int b = blk >> 6, d = blk & 63;
    const int tid = threadIdx.x;
    float* ctx_out = cat + (size_t)(b * Tdim + d) * 1024 + 512;

    if (d >= dec_len[b]) {
        for (int h = tid; h < Hdim; h += 256) ctx_out[h] = 0.f;
        return;
    }
    const int Tv = enc_len[b];

    __shared__ float part[64][4];
    __shared__ float a_lds[64];

    const int e = tid >> 2, p = tid & 3;
    float s = 0.f;
    if (e < Tv) {
        const float* ep = encp + (size_t)(b * Tdim + e) * Hdim;
        const float* dp = decp + (size_t)(b * Tdim + d) * Hdim;
        const int g0 = p * 128;
        for (int g = g0; g < g0 + 128; ++g)
            s += vw[g] * tanhf(ep[g] + dp[g] + battn[g]);
    }
    part[e][p] = s;
    __syncthreads();

    if (tid < 64) {
        const int e2 = tid;
        float en = (e2 < Tv) ? (part[e2][0] + part[e2][1] + part[e2][2] + part[e2][3] + vb[0]) : -1e30f;
        float m = en;
#pragma unroll
        for (int off = 32; off; off >>= 1) m = fmaxf(m, __shfl_xor(m, off));
        float ex = (e2 < Tv) ? __expf(en - m) : 0.f;
        float sum = ex;
#pragma unroll
        for (int off = 32; off; off >>= 1) sum += __shfl_xor(sum, off);
        a_lds[e2] = ex / sum;
    }
    __syncthreads();

    const int h = tid * 2;
    float c0 = 0.f, c1 = 0.f;
    for (int e3 = 0; e3 < Tv; ++e3) {
        float a = a_lds[e3];
        float2 ev = *(const float2*)(enc + (size_t)(b * Tdim + e3) * Hdim + h);
        c0 += a * ev.x; c1 += a * ev.y;
    }
    float2 cv; cv.x = c0; cv.y = c1;
    *(float2*)(ctx_out + h) = cv;
}

// --------------------------- logits bf16 MFMA GEMM -------------------------
// C(1024 x 32000) = A(1024x512 bf16) @ B(32000x512 bf16)^T + bias, fp32 out
// 128x128 tile, BK=32, 4 waves, each wave 64x64 via 4x4 MFMA 16x16x32

__global__ __launch_bounds__(256) void gemm_logits(
    const unsigned short* __restrict__ A,
    const unsigned short* __restrict__ B,
    const float* __restrict__ bias,
    float* __restrict__ C)
{
    const int K = Hdim;
    __shared__ unsigned short As[128 * 40];
    __shared__ unsigned short Bs[128 * 40];
    const int tid = threadIdx.x;
    const int m0 = blockIdx.y * 128, n0 = blockIdx.x * 128;
    const int wave = tid >> 6, lane = tid & 63;
    const int wm = (wave >> 1) * 64, wn = (wave & 1) * 64;
    const int lrow = lane & 15, lk = (lane >> 4) * 8;

    f32x4 acc[4][4];
#pragma unroll
    for (int i = 0; i < 4; ++i)
#pragma unroll
        for (int j = 0; j < 4; ++j) acc[i][j] = (f32x4){0.f, 0.f, 0.f, 0.f};

    for (int k0 = 0; k0 < K; k0 += 32) {
#pragma unroll
        for (int i = 0; i < 2; ++i) {
            int idx = tid + i * 256;        // 0..511
            int rr = idx >> 2, kq = (idx & 3) * 8;
            *(uint4*)(&As[rr * 40 + kq]) = *(const uint4*)(A + (size_t)(m0 + rr) * K + k0 + kq);
            *(uint4*)(&Bs[rr * 40 + kq]) = *(const uint4*)(B + (size_t)(n0 + rr) * K + k0 + kq);
        }
        __syncthreads();
        bf16x8 af[4], bf[4];
#pragma unroll
        for (int i = 0; i < 4; ++i) af[i] = *(const bf16x8*)(&As[(wm + i * 16 + lrow) * 40 + lk]);
#pragma unroll
        for (int j = 0; j < 4; ++j) bf[j] = *(const bf16x8*)(&Bs[(wn + j * 16 + lrow) * 40 + lk]);
#pragma unroll
        for (int i = 0; i < 4; ++i)
#pragma unroll
            for (int j = 0; j < 4; ++j)
                acc[i][j] = __builtin_amdgcn_mfma_f32_16x16x32_bf16(af[i], bf[j], acc[i][j], 0, 0, 0);
        __syncthreads();
    }

    const int crow = m0 + wm + ((lane >> 4) * 4);
    const int ccol = n0 + wn + (lane & 15);
#pragma unroll
    for (int i = 0; i < 4; ++i) {
#pragma unroll
        for (int j = 0; j < 4; ++j) {
            int col = ccol + j * 16;
            float bv = bias[col];
#pragma unroll
            for (int rr = 0; rr < 4; ++rr) {
                int row = crow + i * 16 + rr;
                C[(size_t)row * Vdim + col] = acc[i][j][rr] + bv;
            }
        }
    }
}

// ------------------------------- launcher ----------------------------------

extern "C" void kernel_launch(void* const* d_in, const int* in_sizes, int n_in,
                              void* d_out, int out_size, void* d_ws, size_t ws_size,
                              hipStream_t stream) {
    (void)in_sizes; (void)n_in; (void)out_size; (void)ws_size;

    const float* input_seqs  = (const float*)d_in[0];
    const int*   input_len   = (const int*)  d_in[1];
    const float* enc_out     = (const float*)d_in[2];
    const int*   enc_len     = (const int*)  d_in[3];
    const float* W_ih        = (const float*)d_in[4];
    const float* W_hh        = (const float*)d_in[5];
    const float* b_ih        = (const float*)d_in[6];
    const float* b_hh        = (const float*)d_in[7];
    const float* W_attn      = (const float*)d_in[8];
    const float* b_attn      = (const float*)d_in[9];
    const float* v_w         = (const float*)d_in[10];
    const float* v_b         = (const float*)d_in[11];
    const float* W_dense     = (const float*)d_in[12];
    const float* b_dense     = (const float*)d_in[13];
    const float* W_out       = (const float*)d_in[14];
    const float* b_out       = (const float*)d_in[15];

    float* logits = (float*)d_out;                        // (1024, 32000)
    float* h_last = (float*)d_out + (size_t)BT * Vdim;    // (16, 512)

    // workspace layout (float slots)
    float* ws = (float*)d_ws;
    float* xp      = ws;                        // 1024*1536
    float* encp    = xp      + 1572864;         // 1024*512
    float* decp    = encp    + 524288;          // 1024*512
    float* cat     = decp    + 524288;          // 1024*1024
    float* dense   = cat     + 1048576;         // 1024*512
    float* hbuf    = dense   + 524288;          // 2*16*512
    int*   flags   = (int*)(hbuf + 16384);      // 128
    float* zbias   = (float*)(flags + 128);     // 512
    unsigned short* Wout_bf  = (unsigned short*)(zbias + 512);        // 32000*512 bf16
    unsigned short* dense_bf = Wout_bf + (size_t)Vdim * Hdim;         // 1024*512 bf16

    // 1. zero-init: hbuf (16384) + flags (128) + zbias (512) contiguous
    zero_kernel<<<(16384 + 128 + 512 + 255) / 256, 256, 0, stream>>>(hbuf, 16384 + 128 + 512);
    f32_to_bf16_kernel<<<2048, 256, 0, stream>>>(W_out, Wout_bf, Vdim * Hdim);

    // 2. x_proj = input_seqs @ W_ih^T + b_ih        (1024 x 1536, K=512)
    gemm_f32<<<dim3(1536 / 64, BT / 64), 256, 0, stream>>>(
        input_seqs, Hdim, W_ih, Hdim, b_ih, xp, 1536, Hdim, 0);

    // 3. enc_p = enc @ We^T (We = W_attn[:, :512], ldb=1024), no bias
    gemm_f32<<<dim3(Hdim / 64, BT / 64), 256, 0, stream>>>(
        enc_out, Hdim, W_attn, 1024, zbias, encp, Hdim, Hdim, 0);

    // 4. GRU: persistent kernel, 64 steps internally
    gru_persistent<<<GRU_BLOCKS, 256, 0, stream>>>(
        xp, W_hh, b_hh, input_len, hbuf, flags, cat, h_last);

    // 5. dec_p = dec_out @ Wd^T (Wd = W_attn[:, 512:], ldb=1024), no bias
    gemm_f32<<<dim3(Hdim / 64, BT / 64), 256, 0, stream>>>(
        cat, 1024, W_attn + 512, 1024, zbias, decp, Hdim, Hdim, 0);

    // 6. attention -> cat[:, 512:1024]
    attn_kernel<<<BT, 256, 0, stream>>>(encp, decp, enc_out, b_attn, v_w, v_b,
                                        enc_len, input_len, cat);

    // 7. dense = tanh(cat @ W_dense^T + b_dense)   (1024 x 512, K=1024)
    gemm_f32<<<dim3(Hdim / 64, BT / 64), 256, 0, stream>>>(
        cat, 1024, W_dense, 1024, b_dense, dense, Hdim, 1024, 1);

    // 8. dense -> bf16
    f32_to_bf16_kernel<<<512, 256, 0, stream>>>(dense, dense_bf, BT * Hdim);

    // 9. logits = dense @ W_out^T + b_out   (1024 x 32000, K=512) bf16 MFMA
    gemm_logits<<<dim3(Vdim / 128, BT / 128), 256, 0, stream>>>(
        dense_bf, Wout_bf, b_out, logits);
}

// Round 3
// 1225.142 us; speedup vs baseline: 1.5996x; 1.5996x over previous
//
#include <hip/hip_runtime.h>
#include <stdint.h>

// ---------------------------------------------------------------------------
// Decoder: GRU(seq) + attention + dense + vocab projection
// H=512, V=32000, B=16, Td=Te=64
// Round 3: persistent GRU with FENCE-FREE grid barrier. All cross-block data
// (h state, flags) moves via relaxed agent-scope atomics (sc1, L2-bypassing,
// device-coherent). NO __threadfence / acquire / release -> no buffer_wbl2 /
// buffer_inv storms (round-2 lesson: those cost 440 MB of HBM churn and
// 23.5 us/step). Producer ordering: s_waitcnt(0) drains own sc1 stores before
// the relaxed flag store; consumer ordering: poll-loop control dependency +
// in-order wave issue.
// ---------------------------------------------------------------------------

#define Hdim 512
#define Vdim 32000
#define Bdim 16
#define Tdim 64
#define BT   1024   // B*Td rows
#define GRU_BLOCKS 128

typedef __attribute__((ext_vector_type(8))) short bf16x8;
typedef __attribute__((ext_vector_type(4))) float f32x4;

static __device__ __forceinline__ unsigned short f2bf(float f) {
    unsigned u = __float_as_uint(f);
    u = u + 0x7FFFu + ((u >> 16) & 1u);   // round-to-nearest-even
    return (unsigned short)(u >> 16);
}

// --------------------------- small utility kernels -------------------------

__global__ void zero_kernel(float* p, int n) {
    int i = blockIdx.x * 256 + threadIdx.x;
    if (i < n) p[i] = 0.f;
}

__global__ void f32_to_bf16_kernel(const float* __restrict__ in, unsigned short* __restrict__ out, int n) {
    int i = blockIdx.x * 256 + threadIdx.x;
    int stride = gridDim.x * 256;
    for (; i < n; i += stride) out[i] = f2bf(in[i]);
}

// --------------------------- generic fp32 GEMM -----------------------------
// C[M x N] = act( A(M x K, lda) @ B(N x K, ldb)^T + bias ), dims %64==0, K%16==0
// grid = (N/64, M/64), block = 256

__global__ __launch_bounds__(256) void gemm_f32(
    const float* __restrict__ A, int lda,
    const float* __restrict__ B, int ldb,
    const float* __restrict__ bias,
    float* __restrict__ C, int ldc,
    int K, int act)
{
    __shared__ float As[16][68];
    __shared__ float Bs[16][68];
    const int tid = threadIdx.x;
    const int tx = tid & 15, ty = tid >> 4;
    const int m0 = blockIdx.y * 64, n0 = blockIdx.x * 64;

    float acc[4][4];
#pragma unroll
    for (int i = 0; i < 4; ++i)
#pragma unroll
        for (int j = 0; j < 4; ++j) acc[i][j] = 0.f;

    const int r  = tid >> 2;        // 0..63
    const int kq = (tid & 3) * 4;   // 0,4,8,12

    for (int k0 = 0; k0 < K; k0 += 16) {
        float4 a4 = *(const float4*)(A + (size_t)(m0 + r) * lda + k0 + kq);
        float4 b4 = *(const float4*)(B + (size_t)(n0 + r) * ldb + k0 + kq);
        As[kq + 0][r] = a4.x; As[kq + 1][r] = a4.y; As[kq + 2][r] = a4.z; As[kq + 3][r] = a4.w;
        Bs[kq + 0][r] = b4.x; Bs[kq + 1][r] = b4.y; Bs[kq + 2][r] = b4.z; Bs[kq + 3][r] = b4.w;
        __syncthreads();
#pragma unroll
        for (int k = 0; k < 16; ++k) {
            float4 av = *(const float4*)(&As[k][ty * 4]);
            float4 bv = *(const float4*)(&Bs[k][tx * 4]);
            acc[0][0] += av.x * bv.x; acc[0][1] += av.x * bv.y; acc[0][2] += av.x * bv.z; acc[0][3] += av.x * bv.w;
            acc[1][0] += av.y * bv.x; acc[1][1] += av.y * bv.y; acc[1][2] += av.y * bv.z; acc[1][3] += av.y * bv.w;
            acc[2][0] += av.z * bv.x; acc[2][1] += av.z * bv.y; acc[2][2] += av.z * bv.z; acc[2][3] += av.z * bv.w;
            acc[3][0] += av.w * bv.x; acc[3][1] += av.w * bv.y; acc[3][2] += av.w * bv.z; acc[3][3] += av.w * bv.w;
        }
        __syncthreads();
    }

    const float4 bv4 = *(const float4*)(bias + n0 + tx * 4);
#pragma unroll
    for (int i = 0; i < 4; ++i) {
        int row = m0 + ty * 4 + i;
        float4 v;
        v.x = acc[i][0] + bv4.x; v.y = acc[i][1] + bv4.y;
        v.z = acc[i][2] + bv4.z; v.w = acc[i][3] + bv4.w;
        if (act == 1) { v.x = tanhf(v.x); v.y = tanhf(v.y); v.z = tanhf(v.z); v.w = tanhf(v.w); }
        *(float4*)(C + (size_t)row * ldc + n0 + tx * 4) = v;
    }
}

// --------------------------- persistent GRU --------------------------------
// 128 blocks x 256 threads, co-resident. Block bid owns hidden units
// j0=bid*4..j0+3 (12 W_hh rows, in registers: lane l holds k-slice l*8..+7).
// h state exchanged via RELAXED agent-scope atomics (sc1) only.

static __device__ __forceinline__ float agent_ld(const float* p) {
    return __hip_atomic_load(p, __ATOMIC_RELAXED, __HIP_MEMORY_SCOPE_AGENT);
}
static __device__ __forceinline__ void agent_st(float* p, float v) {
    __hip_atomic_store(p, v, __ATOMIC_RELAXED, __HIP_MEMORY_SCOPE_AGENT);
}

__global__ __launch_bounds__(256) void gru_persistent(
    const float* __restrict__ xp,        // (1024,1536) rows = b*64+t
    const float* __restrict__ Whh,       // (1536,512)
    const float* __restrict__ bhh,       // (1536)
    const int*   __restrict__ lengths,   // (16)
    float* __restrict__ hbuf,            // (2,16,512); buf0 zero-initialized
    int*   __restrict__ flags,           // (128) zero-initialized
    float* __restrict__ cat,             // (1024,1024) write cols [0,512)
    float* __restrict__ h_last)          // (16,512)
{
    const int bid  = blockIdx.x;
    const int tid  = threadIdx.x;
    const int wave = tid >> 6, lane = tid & 63;
    const int j0 = bid * 4;
    const int k0 = lane * 8;

    // --- load W_hh slice into registers (once, ordinary cached loads) ---
    float w[12][8];
#pragma unroll
    for (int g = 0; g < 3; ++g)
#pragma unroll
        for (int jj = 0; jj < 4; ++jj) {
            const float* src = Whh + (size_t)(g * 512 + j0 + jj) * Hdim + k0;
            float4 a = *(const float4*)src;
            float4 b = *(const float4*)(src + 4);
            int r = g * 4 + jj;
            w[r][0] = a.x; w[r][1] = a.y; w[r][2] = a.z; w[r][3] = a.w;
            w[r][4] = b.x; w[r][5] = b.y; w[r][6] = b.z; w[r][7] = b.w;
        }

    // gate-lane precomputation
    const int gjj = lane >> 2;        // 0..3 (valid when lane<16)
    const int gbi = lane & 3;
    const int gb  = wave * 4 + gbi;
    const int gj  = j0 + gjj;
    float bh_r = 0.f, bh_z = 0.f, bh_n = 0.f;
    int   len_b = 0;
    if (lane < 16) {
        bh_r = bhh[gj]; bh_z = bhh[512 + gj]; bh_n = bhh[1024 + gj];
        len_b = lengths[gb];
    }

    for (int t = 0; t < Tdim; ++t) {
        float* hcur = hbuf + (t & 1) * (Bdim * Hdim);
        float* hnxt = hbuf + ((t + 1) & 1) * (Bdim * Hdim);

        float p[12][4];
#pragma unroll
        for (int r = 0; r < 12; ++r)
#pragma unroll
            for (int bi = 0; bi < 4; ++bi) p[r][bi] = 0.f;

#pragma unroll
        for (int bi = 0; bi < 4; ++bi) {
            const int b = wave * 4 + bi;
            const unsigned long long* hp =
                (const unsigned long long*)(hcur + b * Hdim + k0);
            float hv[8];
#pragma unroll
            for (int q = 0; q < 4; ++q) {
                unsigned long long u =
                    __hip_atomic_load(hp + q, __ATOMIC_RELAXED, __HIP_MEMORY_SCOPE_AGENT);
                union { unsigned long long u; float f[2]; } cv; cv.u = u;
                hv[q * 2]     = cv.f[0];
                hv[q * 2 + 1] = cv.f[1];
            }
#pragma unroll
            for (int r = 0; r < 12; ++r)
#pragma unroll
                for (int k = 0; k < 8; ++k)
                    p[r][bi] += w[r][k] * hv[k];
        }

        // butterfly reduce across 64 lanes
#pragma unroll
        for (int off = 1; off < 64; off <<= 1)
#pragma unroll
            for (int r = 0; r < 12; ++r)
#pragma unroll
                for (int bi = 0; bi < 4; ++bi)
                    p[r][bi] += __shfl_xor(p[r][bi], off);

        if (lane < 16) {
            float hr = p[0 + gjj][gbi] + bh_r;
            float hz = p[4 + gjj][gbi] + bh_z;
            float hn = p[8 + gjj][gbi] + bh_n;
            const float* xrow = xp + (size_t)(gb * Tdim + t) * 1536;
            float xr = xrow[gj], xz = xrow[512 + gj], xn = xrow[1024 + gj];
            float rg = 1.f / (1.f + __expf(-(xr + hr)));
            float zg = 1.f / (1.f + __expf(-(xz + hz)));
            float ng = tanhf(xn + rg * hn);
            float hold = agent_ld(hcur + gb * Hdim + gj);
            float hnew = (1.f - zg) * ng + zg * hold;
            bool valid = t < len_b;
            float hkeep = valid ? hnew : hold;
            agent_st(hnxt + gb * Hdim + gj, hkeep);
            cat[(size_t)(gb * Tdim + t) * 1024 + gj] = valid ? hnew : 0.f;  // ordinary
            if (t == Tdim - 1) h_last[gb * Hdim + gj] = hkeep;              // ordinary
        }

        // ---- fence-free grid barrier ----
        if (t == Tdim - 1) break;
        __asm__ volatile("" ::: "memory");
        __builtin_amdgcn_s_waitcnt(0);     // drain this wave's sc1 stores
        __asm__ volatile("" ::: "memory");
        __syncthreads();                   // all waves of block drained
        if (tid == 0)
            __hip_atomic_store(&flags[bid], t + 1, __ATOMIC_RELAXED, __HIP_MEMORY_SCOPE_AGENT);
        if (tid < GRU_BLOCKS) {
            while (__hip_atomic_load(&flags[tid], __ATOMIC_RELAXED, __HIP_MEMORY_SCOPE_AGENT) < t + 1)
                __builtin_amdgcn_s_sleep(2);
        }
        __syncthreads();
        __asm__ volatile("" ::: "memory");
    }
}

// ------------------------------ attention ----------------------------------
// one block per (b,d); energies -> softmax over valid e -> context
// writes cat[:, 512:1024]

__global__ __launch_bounds__(256) void attn_kernel(
    const float* __restrict__ encp,     // (1024,512)
    const float* __restrict__ decp,     // (1024,512)
    const float* __restrict__ enc,      // (16,64,512)
    const float* __restrict__ battn,    // (512)
    const float* __restrict__ vw,       // (512)
    const float* __restrict__ vb,       // (1)
    const int* __restrict__ enc_len,    // (16)
    const int* __restrict__ dec_len,    // (16)
    float* __restrict__ cat)            // (1024,1024)
{
    const int blk = blockIdx.x;
    const int b = blk >> 6, d = blk & 63;
    const int tid = threadIdx.x;
    float* ctx_out = cat + (size_t)(b * Tdim + d) * 1024 + 512;

    if (d >= dec_len[b]) {
        for (int h = tid; h < Hdim; h += 256) ctx_out[h] = 0.f;
        return;
    }
    const int Tv = enc_len[b];

    __shared__ float part[64][4];
    __shared__ float a_lds[64];

    const int e = tid >> 2, p = tid & 3;
    float s = 0.f;
    if (e < Tv) {
        const float* ep = encp + (size_t)(b * Tdim + e) * Hdim;
        const float* dp = decp + (size_t)(b * Tdim + d) * Hdim;
        const int g0 = p * 128;
        for (int g = g0; g < g0 + 128; ++g)
            s += vw[g] * tanhf(ep[g] + dp[g] + battn[g]);
    }
    part[e][p] = s;
    __syncthreads();

    if (tid < 64) {
        const int e2 = tid;
        float en = (e2 < Tv) ? (part[e2][0] + part[e2][1] + part[e2][2] + part[e2][3] + vb[0]) : -1e30f;
        float m = en;
#pragma unroll
        for (int off = 32; off; off >>= 1) m = fmaxf(m, __shfl_xor(m, off));
        float ex = (e2 < Tv) ? __expf(en - m) : 0.f;
        float sum = ex;
#pragma unroll
        for (int off = 32; off; off >>= 1) sum += __shfl_xor(sum, off);
        a_lds[e2] = ex / sum;
    }
    __syncthreads();

    const int h = tid * 2;
    float c0 = 0.f, c1 = 0.f;
    for (int e3 = 0; e3 < Tv; ++e3) {
        float a = a_lds[e3];
        float2 ev = *(const float2*)(enc + (size_t)(b * Tdim + e3) * Hdim + h);
        c0 += a * ev.x; c1 += a * ev.y;
    }
    float2 cv; cv.x = c0; cv.y = c1;
    *(float2*)(ctx_out + h) = cv;
}

// --------------------------- logits bf16 MFMA GEMM -------------------------
// C(1024 x 32000) = A(1024x512 bf16) @ B(32000x512 bf16)^T + bias, fp32 out
// 128x128 tile, BK=32, 4 waves, each wave 64x64 via 4x4 MFMA 16x16x32

__global__ __launch_bounds__(256) void gemm_logits(
    const unsigned short* __restrict__ A,
    const unsigned short* __restrict__ B,
    const float* __restrict__ bias,
    float* __restrict__ C)
{
    const int K = Hdim;
    __shared__ unsigned short As[128 * 40];
    __shared__ unsigned short Bs[128 * 40];
    const int tid = threadIdx.x;
    const int m0 = blockIdx.y * 128, n0 = blockIdx.x * 128;
    const int wave = tid >> 6, lane = tid & 63;
    const int wm = (wave >> 1) * 64, wn = (wave & 1) * 64;
    const int lrow = lane & 15, lk = (lane >> 4) * 8;

    f32x4 acc[4][4];
#pragma unroll
    for (int i = 0; i < 4; ++i)
#pragma unroll
        for (int j = 0; j < 4; ++j) acc[i][j] = (f32x4){0.f, 0.f, 0.f, 0.f};

    for (int k0 = 0; k0 < K; k0 += 32) {
#pragma unroll
        for (int i = 0; i < 2; ++i) {
            int idx = tid + i * 256;        // 0..511
            int rr = idx >> 2, kq = (idx & 3) * 8;
            *(uint4*)(&As[rr * 40 + kq]) = *(const uint4*)(A + (size_t)(m0 + rr) * K + k0 + kq);
            *(uint4*)(&Bs[rr * 40 + kq]) = *(const uint4*)(B + (size_t)(n0 + rr) * K + k0 + kq);
        }
        __syncthreads();
        bf16x8 af[4], bf[4];
#pragma unroll
        for (int i = 0; i < 4; ++i) af[i] = *(const bf16x8*)(&As[(wm + i * 16 + lrow) * 40 + lk]);
#pragma unroll
        for (int j = 0; j < 4; ++j) bf[j] = *(const bf16x8*)(&Bs[(wn + j * 16 + lrow) * 40 + lk]);
#pragma unroll
        for (int i = 0; i < 4; ++i)
#pragma unroll
            for (int j = 0; j < 4; ++j)
                acc[i][j] = __builtin_amdgcn_mfma_f32_16x16x32_bf16(af[i], bf[j], acc[i][j], 0, 0, 0);
        __syncthreads();
    }

    const int crow = m0 + wm + ((lane >> 4) * 4);
    const int ccol = n0 + wn + (lane & 15);
#pragma unroll
    for (int i = 0; i < 4; ++i) {
#pragma unroll
        for (int j = 0; j < 4; ++j) {
            int col = ccol + j * 16;
            float bv = bias[col];
#pragma unroll
            for (int rr = 0; rr < 4; ++rr) {
                int row = crow + i * 16 + rr;
                C[(size_t)row * Vdim + col] = acc[i][j][rr] + bv;
            }
        }
    }
}

// ------------------------------- launcher ----------------------------------

extern "C" void kernel_launch(void* const* d_in, const int* in_sizes, int n_in,
                              void* d_out, int out_size, void* d_ws, size_t ws_size,
                              hipStream_t stream) {
    (void)in_sizes; (void)n_in; (void)out_size; (void)ws_size;

    const float* input_seqs  = (const float*)d_in[0];
    const int*   input_len   = (const int*)  d_in[1];
    const float* enc_out     = (const float*)d_in[2];
    const int*   enc_len     = (const int*)  d_in[3];
    const float* W_ih        = (const float*)d_in[4];
    const float* W_hh        = (const float*)d_in[5];
    const float* b_ih        = (const float*)d_in[6];
    const float* b_hh        = (const float*)d_in[7];
    const float* W_attn      = (const float*)d_in[8];
    const float* b_attn      = (const float*)d_in[9];
    const float* v_w         = (const float*)d_in[10];
    const float* v_b         = (const float*)d_in[11];
    const float* W_dense     = (const float*)d_in[12];
    const float* b_dense     = (const float*)d_in[13];
    const float* W_out       = (const float*)d_in[14];
    const float* b_out       = (const float*)d_in[15];

    float* logits = (float*)d_out;                        // (1024, 32000)
    float* h_last = (float*)d_out + (size_t)BT * Vdim;    // (16, 512)

    // workspace layout (float slots)
    float* ws = (float*)d_ws;
    float* xp      = ws;                        // 1024*1536
    float* encp    = xp      + 1572864;         // 1024*512
    float* decp    = encp    + 524288;          // 1024*512
    float* cat     = decp    + 524288;          // 1024*1024
    float* dense   = cat     + 1048576;         // 1024*512
    float* hbuf    = dense   + 524288;          // 2*16*512
    int*   flags   = (int*)(hbuf + 16384);      // 128
    float* zbias   = (float*)(flags + 128);     // 512
    unsigned short* Wout_bf  = (unsigned short*)(zbias + 512);        // 32000*512 bf16
    unsigned short* dense_bf = Wout_bf + (size_t)Vdim * Hdim;         // 1024*512 bf16

    // 1. zero-init: hbuf (16384) + flags (128) + zbias (512) contiguous
    zero_kernel<<<(16384 + 128 + 512 + 255) / 256, 256, 0, stream>>>(hbuf, 16384 + 128 + 512);
    f32_to_bf16_kernel<<<2048, 256, 0, stream>>>(W_out, Wout_bf, Vdim * Hdim);

    // 2. x_proj = input_seqs @ W_ih^T + b_ih        (1024 x 1536, K=512)
    gemm_f32<<<dim3(1536 / 64, BT / 64), 256, 0, stream>>>(
        input_seqs, Hdim, W_ih, Hdim, b_ih, xp, 1536, Hdim, 0);

    // 3. enc_p = enc @ We^T (We = W_attn[:, :512], ldb=1024), no bias
    gemm_f32<<<dim3(Hdim / 64, BT / 64), 256, 0, stream>>>(
        enc_out, Hdim, W_attn, 1024, zbias, encp, Hdim, Hdim, 0);

    // 4. GRU: persistent kernel, 64 steps internally
    gru_persistent<<<GRU_BLOCKS, 256, 0, stream>>>(
        xp, W_hh, b_hh, input_len, hbuf, flags, cat, h_last);

    // 5. dec_p = dec_out @ Wd^T (Wd = W_attn[:, 512:], ldb=1024), no bias
    gemm_f32<<<dim3(Hdim / 64, BT / 64), 256, 0, stream>>>(
        cat, 1024, W_attn + 512, 1024, zbias, decp, Hdim, Hdim, 0);

    // 6. attention -> cat[:, 512:1024]
    attn_kernel<<<BT, 256, 0, stream>>>(encp, decp, enc_out, b_attn, v_w, v_b,
                                        enc_len, input_len, cat);

    // 7. dense = tanh(cat @ W_dense^T + b_dense)   (1024 x 512, K=1024)
    gemm_f32<<<dim3(Hdim / 64, BT / 64), 256, 0, stream>>>(
        cat, 1024, W_dense, 1024, b_dense, dense, Hdim, 1024, 1);

    // 8. dense -> bf16
    f32_to_bf16_kernel<<<512, 256, 0, stream>>>(dense, dense_bf, BT * Hdim);

    // 9. logits = dense @ W_out^T + b_out   (1024 x 32000, K=512) bf16 MFMA
    gemm_logits<<<dim3(Vdim / 128, BT / 128), 256, 0, stream>>>(
        dense_bf, Wout_bf, b_out, logits);
}

// Round 4
// 1075.645 us; speedup vs baseline: 1.8219x; 1.1390x over previous
//
#include <hip/hip_runtime.h>
#include <stdint.h>

// ---------------------------------------------------------------------------
// Decoder: GRU(seq) + attention + dense + vocab projection
// H=512, V=32000, B=16, Td=Te=64
// Round 4:
//  - GRU barrier: centralized atomicAdd arrive-counter + single padded "go"
//    word, tid==0-only polling (round-3 lesson: 128x128 pollers on 2 cache
//    lines serialized at LLC -> 11 us/step stall).
//  - All former fp32 GEMMs -> split-bf16 MFMA (A=Ah+Al, B=Bh+Bl, compute
//    AhBh+AhBl+AlBh, fp32 accumulate): ~1.6e-5 relative error, MFMA rate.
//  - cat matrix stored as hi/lo bf16 pairs written directly by GRU/attn.
// ---------------------------------------------------------------------------

#define Hdim 512
#define Vdim 32000
#define Bdim 16
#define Tdim 64
#define BT   1024   // B*Td rows
#define GRU_BLOCKS 128

typedef __attribute__((ext_vector_type(8))) short bf16x8;
typedef __attribute__((ext_vector_type(4))) float f32x4;

static __device__ __forceinline__ unsigned short f2bf(float f) {
    unsigned u = __float_as_uint(f);
    u = u + 0x7FFFu + ((u >> 16) & 1u);   // RNE
    return (unsigned short)(u >> 16);
}
static __device__ __forceinline__ float bf2f(unsigned short h) {
    return __uint_as_float((unsigned)h << 16);
}

// --------------------------- small utility kernels -------------------------

__global__ void zero_kernel(float* p, int n) {
    int i = blockIdx.x * 256 + threadIdx.x;
    if (i < n) p[i] = 0.f;
}

// vectorized f32 -> bf16 (n % 4 == 0)
__global__ void f32_to_bf16_kernel(const float* __restrict__ in,
                                   unsigned short* __restrict__ out, int n) {
    int i = (blockIdx.x * 256 + threadIdx.x) * 4;
    int stride = gridDim.x * 256 * 4;
    for (; i < n; i += stride) {
        float4 v = *(const float4*)(in + i);
        unsigned short h[4] = {f2bf(v.x), f2bf(v.y), f2bf(v.z), f2bf(v.w)};
        *(uint2*)(out + i) = *(const uint2*)h;
    }
}

// f32 -> (hi bf16, lo bf16) split (n % 4 == 0)
__global__ void split_bf16_kernel(const float* __restrict__ in,
                                  unsigned short* __restrict__ hi,
                                  unsigned short* __restrict__ lo, int n) {
    int i = (blockIdx.x * 256 + threadIdx.x) * 4;
    int stride = gridDim.x * 256 * 4;
    for (; i < n; i += stride) {
        float4 v = *(const float4*)(in + i);
        float f[4] = {v.x, v.y, v.z, v.w};
        unsigned short h[4], l[4];
#pragma unroll
        for (int k = 0; k < 4; ++k) {
            h[k] = f2bf(f[k]);
            l[k] = f2bf(f[k] - bf2f(h[k]));
        }
        *(uint2*)(hi + i) = *(const uint2*)h;
        *(uint2*)(lo + i) = *(const uint2*)l;
    }
}

// ----------------------- split-bf16 MFMA GEMM ------------------------------
// C[M x N] = act( A @ B^T + bias ),  A ~ (Ah+Al) (M x K, lda elements),
// B ~ (Bh+Bl) (N x K, ldb). M,N % 128 == 0, K % 32 == 0.
// acc = Ah*Bh + Ah*Bl + Al*Bh  (Al*Bl dropped, ~1e-5 rel).
// If Cb != null, write bf16 to Cb instead of fp32 to C.
// grid = (N/128, M/128), block = 256.

__global__ __launch_bounds__(256) void gemm_split(
    const unsigned short* __restrict__ Ah, const unsigned short* __restrict__ Al, int lda,
    const unsigned short* __restrict__ Bh, const unsigned short* __restrict__ Bl, int ldb,
    const float* __restrict__ bias,
    float* __restrict__ C, unsigned short* __restrict__ Cb, int ldc,
    int K, int act)
{
    __shared__ unsigned short AsH[128 * 40];
    __shared__ unsigned short AsL[128 * 40];
    __shared__ unsigned short BsH[128 * 40];
    __shared__ unsigned short BsL[128 * 40];
    const int tid = threadIdx.x;
    const int m0 = blockIdx.y * 128, n0 = blockIdx.x * 128;
    const int wave = tid >> 6, lane = tid & 63;
    const int wm = (wave >> 1) * 64, wn = (wave & 1) * 64;
    const int lrow = lane & 15, lk = (lane >> 4) * 8;

    f32x4 acc[4][4];
#pragma unroll
    for (int i = 0; i < 4; ++i)
#pragma unroll
        for (int j = 0; j < 4; ++j) acc[i][j] = (f32x4){0.f, 0.f, 0.f, 0.f};

    for (int k0 = 0; k0 < K; k0 += 32) {
#pragma unroll
        for (int i = 0; i < 2; ++i) {
            int idx = tid + i * 256;        // 0..511
            int rr = idx >> 2, kq = (idx & 3) * 8;
            size_t ao = (size_t)(m0 + rr) * lda + k0 + kq;
            size_t bo = (size_t)(n0 + rr) * ldb + k0 + kq;
            *(uint4*)(&AsH[rr * 40 + kq]) = *(const uint4*)(Ah + ao);
            *(uint4*)(&AsL[rr * 40 + kq]) = *(const uint4*)(Al + ao);
            *(uint4*)(&BsH[rr * 40 + kq]) = *(const uint4*)(Bh + bo);
            *(uint4*)(&BsL[rr * 40 + kq]) = *(const uint4*)(Bl + bo);
        }
        __syncthreads();
        bf16x8 ah[4], al[4], bh[4], bl[4];
#pragma unroll
        for (int i = 0; i < 4; ++i) {
            ah[i] = *(const bf16x8*)(&AsH[(wm + i * 16 + lrow) * 40 + lk]);
            al[i] = *(const bf16x8*)(&AsL[(wm + i * 16 + lrow) * 40 + lk]);
        }
#pragma unroll
        for (int j = 0; j < 4; ++j) {
            bh[j] = *(const bf16x8*)(&BsH[(wn + j * 16 + lrow) * 40 + lk]);
            bl[j] = *(const bf16x8*)(&BsL[(wn + j * 16 + lrow) * 40 + lk]);
        }
#pragma unroll
        for (int i = 0; i < 4; ++i)
#pragma unroll
            for (int j = 0; j < 4; ++j) {
                acc[i][j] = __builtin_amdgcn_mfma_f32_16x16x32_bf16(ah[i], bh[j], acc[i][j], 0, 0, 0);
                acc[i][j] = __builtin_amdgcn_mfma_f32_16x16x32_bf16(ah[i], bl[j], acc[i][j], 0, 0, 0);
                acc[i][j] = __builtin_amdgcn_mfma_f32_16x16x32_bf16(al[i], bh[j], acc[i][j], 0, 0, 0);
            }
        __syncthreads();
    }

    const int crow = m0 + wm + ((lane >> 4) * 4);
    const int ccol = n0 + wn + (lane & 15);
#pragma unroll
    for (int i = 0; i < 4; ++i) {
#pragma unroll
        for (int j = 0; j < 4; ++j) {
            int col = ccol + j * 16;
            float bv = bias[col];
#pragma unroll
            for (int rr = 0; rr < 4; ++rr) {
                int row = crow + i * 16 + rr;
                float v = acc[i][j][rr] + bv;
                if (act == 1) v = tanhf(v);
                if (Cb) Cb[(size_t)row * ldc + col] = f2bf(v);
                else    C [(size_t)row * ldc + col] = v;
            }
        }
    }
}

// --------------------------- persistent GRU --------------------------------
// 128 blocks x 256 threads. Block bid owns hidden units j0=bid*4..+3
// (12 W_hh rows in registers). h exchanged via relaxed agent-scope (sc1).
// Grid barrier: centralized arrive counter + single padded go word,
// tid==0-only polling.

static __device__ __forceinline__ void agent_st(float* p, float v) {
    __hip_atomic_store(p, v, __ATOMIC_RELAXED, __HIP_MEMORY_SCOPE_AGENT);
}

__global__ __launch_bounds__(256) void gru_persistent(
    const float* __restrict__ xp,        // (1024,1536) rows = b*64+t
    const float* __restrict__ Whh,       // (1536,512)
    const float* __restrict__ bhh,       // (1536)
    const int*   __restrict__ lengths,   // (16)
    float* __restrict__ hbuf,            // (2,16,512); zero-initialized
    int*   __restrict__ sync,            // [0]=count, [32]=go; zero-initialized
    unsigned short* __restrict__ cath,   // (1024,1024) cols [0,512)
    unsigned short* __restrict__ catl,
    float* __restrict__ h_last)          // (16,512)
{
    const int bid  = blockIdx.x;
    const int tid  = threadIdx.x;
    const int wave = tid >> 6, lane = tid & 63;
    const int j0 = bid * 4;
    const int k0 = lane * 8;

    // --- W_hh slice into registers (once) ---
    float w[12][8];
#pragma unroll
    for (int g = 0; g < 3; ++g)
#pragma unroll
        for (int jj = 0; jj < 4; ++jj) {
            const float* src = Whh + (size_t)(g * 512 + j0 + jj) * Hdim + k0;
            float4 a = *(const float4*)src;
            float4 b = *(const float4*)(src + 4);
            int r = g * 4 + jj;
            w[r][0] = a.x; w[r][1] = a.y; w[r][2] = a.z; w[r][3] = a.w;
            w[r][4] = b.x; w[r][5] = b.y; w[r][6] = b.z; w[r][7] = b.w;
        }

    const int gjj = lane >> 2;        // 0..3 (valid when lane<16)
    const int gbi = lane & 3;
    const int gb  = wave * 4 + gbi;
    const int gj  = j0 + gjj;
    float bh_r = 0.f, bh_z = 0.f, bh_n = 0.f;
    int   len_b = 0;
    if (lane < 16) {
        bh_r = bhh[gj]; bh_z = bhh[512 + gj]; bh_n = bhh[1024 + gj];
        len_b = lengths[gb];
    }
    float hprev = 0.f;   // this lane's own h[gb][gj] (h0 = 0)

    for (int t = 0; t < Tdim; ++t) {
        const float* hcur = hbuf + (t & 1) * (Bdim * Hdim);
        float*       hnxt = hbuf + ((t + 1) & 1) * (Bdim * Hdim);

        // xp loads are independent of h -> issue early
        float xr = 0.f, xz = 0.f, xn = 0.f;
        if (lane < 16) {
            const float* xrow = xp + (size_t)(gb * Tdim + t) * 1536;
            xr = xrow[gj]; xz = xrow[512 + gj]; xn = xrow[1024 + gj];
        }

        float p[12][4];
#pragma unroll
        for (int r = 0; r < 12; ++r)
#pragma unroll
            for (int bi = 0; bi < 4; ++bi) p[r][bi] = 0.f;

#pragma unroll
        for (int bi = 0; bi < 4; ++bi) {
            const int b = wave * 4 + bi;
            const unsigned long long* hp =
                (const unsigned long long*)(hcur + b * Hdim + k0);
            float hv[8];
#pragma unroll
            for (int q = 0; q < 4; ++q) {
                unsigned long long u =
                    __hip_atomic_load(hp + q, __ATOMIC_RELAXED, __HIP_MEMORY_SCOPE_AGENT);
                union { unsigned long long u; float f[2]; } cv; cv.u = u;
                hv[q * 2]     = cv.f[0];
                hv[q * 2 + 1] = cv.f[1];
            }
#pragma unroll
            for (int r = 0; r < 12; ++r)
#pragma unroll
                for (int k = 0; k < 8; ++k)
                    p[r][bi] += w[r][k] * hv[k];
        }

        // butterfly reduce across 64 lanes
#pragma unroll
        for (int off = 1; off < 64; off <<= 1)
#pragma unroll
            for (int r = 0; r < 12; ++r)
#pragma unroll
                for (int bi = 0; bi < 4; ++bi)
                    p[r][bi] += __shfl_xor(p[r][bi], off);

        if (lane < 16) {
            float hr = p[0 + gjj][gbi] + bh_r;
            float hz = p[4 + gjj][gbi] + bh_z;
            float hn = p[8 + gjj][gbi] + bh_n;
            float rg = 1.f / (1.f + __expf(-(xr + hr)));
            float zg = 1.f / (1.f + __expf(-(xz + hz)));
            float ng = tanhf(xn + rg * hn);
            float hnew = (1.f - zg) * ng + zg * hprev;
            bool valid = t < len_b;
            float hkeep = valid ? hnew : hprev;
            hprev = hkeep;
            agent_st(hnxt + gb * Hdim + gj, hkeep);
            float y = valid ? hnew : 0.f;
            unsigned short yh = f2bf(y);
            size_t ci = (size_t)(gb * Tdim + t) * 1024 + gj;
            cath[ci] = yh;
            catl[ci] = f2bf(y - bf2f(yh));
            if (t == Tdim - 1) h_last[gb * Hdim + gj] = hkeep;
        }

        // ---- grid barrier (centralized counter + go broadcast) ----
        if (t == Tdim - 1) break;
        __asm__ volatile("" ::: "memory");
        __builtin_amdgcn_s_waitcnt(0);     // drain this wave's sc1 stores
        __asm__ volatile("" ::: "memory");
        __syncthreads();                   // whole block drained
        if (tid == 0) {
            int old = __hip_atomic_fetch_add(&sync[0], 1, __ATOMIC_RELAXED,
                                             __HIP_MEMORY_SCOPE_AGENT);
            if (old == GRU_BLOCKS * (t + 1) - 1)
                __hip_atomic_store(&sync[32], t + 1, __ATOMIC_RELAXED,
                                   __HIP_MEMORY_SCOPE_AGENT);
            while (__hip_atomic_load(&sync[32], __ATOMIC_RELAXED,
                                     __HIP_MEMORY_SCOPE_AGENT) < t + 1)
                __builtin_amdgcn_s_sleep(2);
        }
        __syncthreads();
        __asm__ volatile("" ::: "memory");
    }
}

// ------------------------------ attention ----------------------------------
// one block per (b,d); writes context to cat cols [512,1024) as hi/lo bf16

__global__ __launch_bounds__(256) void attn_kernel(
    const float* __restrict__ encp,     // (1024,512)
    const float* __restrict__ decp,     // (1024,512)
    const float* __restrict__ enc,      // (16,64,512)
    const float* __restrict__ battn,    // (512)
    const float* __restrict__ vw,       // (512)
    const float* __restrict__ vb,       // (1)
    const int* __restrict__ enc_len,    // (16)
    const int* __restrict__ dec_len,    // (16)
    unsigned short* __restrict__ cath,
    unsigned short* __restrict__ catl)
{
    const int blk = blockIdx.x;
    const int b = blk >> 6, d = blk & 63;
    const int tid = threadIdx.x;
    const size_t obase = (size_t)(b * Tdim + d) * 1024 + 512;

    if (d >= dec_len[b]) {
        for (int h = tid; h < Hdim; h += 256) { cath[obase + h] = 0; catl[obase + h] = 0; }
        return;
    }
    const int Tv = enc_len[b];

    __shared__ float part[64][4];
    __shared__ float a_lds[64];

    const int e = tid >> 2, p = tid & 3;
    float s = 0.f;
    if (e < Tv) {
        const float* ep = encp + (size_t)(b * Tdim + e) * Hdim;
        const float* dp = decp + (size_t)(b * Tdim + d) * Hdim;
        const int g0 = p * 128;
        for (int g = g0; g < g0 + 128; ++g)
            s += vw[g] * tanhf(ep[g] + dp[g] + battn[g]);
    }
    part[e][p] = s;
    __syncthreads();

    if (tid < 64) {
        const int e2 = tid;
        float en = (e2 < Tv) ? (part[e2][0] + part[e2][1] + part[e2][2] + part[e2][3] + vb[0]) : -1e30f;
        float m = en;
#pragma unroll
        for (int off = 32; off; off >>= 1) m = fmaxf(m, __shfl_xor(m, off));
        float ex = (e2 < Tv) ? __expf(en - m) : 0.f;
        float sum = ex;
#pragma unroll
        for (int off = 32; off; off >>= 1) sum += __shfl_xor(sum, off);
        a_lds[e2] = ex / sum;
    }
    __syncthreads();

    const int h = tid * 2;
    float c0 = 0.f, c1 = 0.f;
    for (int e3 = 0; e3 < Tv; ++e3) {
        float a = a_lds[e3];
        float2 ev = *(const float2*)(enc + (size_t)(b * Tdim + e3) * Hdim + h);
        c0 += a * ev.x; c1 += a * ev.y;
    }
    unsigned short h0 = f2bf(c0), h1 = f2bf(c1);
    cath[obase + h]     = h0;  catl[obase + h]     = f2bf(c0 - bf2f(h0));
    cath[obase + h + 1] = h1;  catl[obase + h + 1] = f2bf(c1 - bf2f(h1));
}

// --------------------------- logits bf16 MFMA GEMM -------------------------
// C(1024 x 32000) = A(1024x512 bf16) @ B(32000x512 bf16)^T + bias, fp32 out

__global__ __launch_bounds__(256) void gemm_logits(
    const unsigned short* __restrict__ A,
    const unsigned short* __restrict__ B,
    const float* __restrict__ bias,
    float* __restrict__ C)
{
    const int K = Hdim;
    __shared__ unsigned short As[128 * 40];
    __shared__ unsigned short Bs[128 * 40];
    const int tid = threadIdx.x;
    const int m0 = blockIdx.y * 128, n0 = blockIdx.x * 128;
    const int wave = tid >> 6, lane = tid & 63;
    const int wm = (wave >> 1) * 64, wn = (wave & 1) * 64;
    const int lrow = lane & 15, lk = (lane >> 4) * 8;

    f32x4 acc[4][4];
#pragma unroll
    for (int i = 0; i < 4; ++i)
#pragma unroll
        for (int j = 0; j < 4; ++j) acc[i][j] = (f32x4){0.f, 0.f, 0.f, 0.f};

    for (int k0 = 0; k0 < K; k0 += 32) {
#pragma unroll
        for (int i = 0; i < 2; ++i) {
            int idx = tid + i * 256;        // 0..511
            int rr = idx >> 2, kq = (idx & 3) * 8;
            *(uint4*)(&As[rr * 40 + kq]) = *(const uint4*)(A + (size_t)(m0 + rr) * K + k0 + kq);
            *(uint4*)(&Bs[rr * 40 + kq]) = *(const uint4*)(B + (size_t)(n0 + rr) * K + k0 + kq);
        }
        __syncthreads();
        bf16x8 af[4], bf[4];
#pragma unroll
        for (int i = 0; i < 4; ++i) af[i] = *(const bf16x8*)(&As[(wm + i * 16 + lrow) * 40 + lk]);
#pragma unroll
        for (int j = 0; j < 4; ++j) bf[j] = *(const bf16x8*)(&Bs[(wn + j * 16 + lrow) * 40 + lk]);
#pragma unroll
        for (int i = 0; i < 4; ++i)
#pragma unroll
            for (int j = 0; j < 4; ++j)
                acc[i][j] = __builtin_amdgcn_mfma_f32_16x16x32_bf16(af[i], bf[j], acc[i][j], 0, 0, 0);
        __syncthreads();
    }

    const int crow = m0 + wm + ((lane >> 4) * 4);
    const int ccol = n0 + wn + (lane & 15);
#pragma unroll
    for (int i = 0; i < 4; ++i) {
#pragma unroll
        for (int j = 0; j < 4; ++j) {
            int col = ccol + j * 16;
            float bv = bias[col];
#pragma unroll
            for (int rr = 0; rr < 4; ++rr) {
                int row = crow + i * 16 + rr;
                C[(size_t)row * Vdim + col] = acc[i][j][rr] + bv;
            }
        }
    }
}

// ------------------------------- launcher ----------------------------------

extern "C" void kernel_launch(void* const* d_in, const int* in_sizes, int n_in,
                              void* d_out, int out_size, void* d_ws, size_t ws_size,
                              hipStream_t stream) {
    (void)in_sizes; (void)n_in; (void)out_size; (void)ws_size;

    const float* input_seqs  = (const float*)d_in[0];
    const int*   input_len   = (const int*)  d_in[1];
    const float* enc_out     = (const float*)d_in[2];
    const int*   enc_len     = (const int*)  d_in[3];
    const float* W_ih        = (const float*)d_in[4];
    const float* W_hh        = (const float*)d_in[5];
    const float* b_ih        = (const float*)d_in[6];
    const float* b_hh        = (const float*)d_in[7];
    const float* W_attn      = (const float*)d_in[8];
    const float* b_attn      = (const float*)d_in[9];
    const float* v_w         = (const float*)d_in[10];
    const float* v_b         = (const float*)d_in[11];
    const float* W_dense     = (const float*)d_in[12];
    const float* b_dense     = (const float*)d_in[13];
    const float* W_out       = (const float*)d_in[14];
    const float* b_out       = (const float*)d_in[15];

    float* logits = (float*)d_out;                        // (1024, 32000)
    float* h_last = (float*)d_out + (size_t)BT * Vdim;    // (16, 512)

    // ---- workspace layout ----
    float* ws    = (float*)d_ws;
    float* xp    = ws;                         // 1572864 f
    float* encp  = xp   + 1572864;             // 524288 f
    float* decp  = encp + 524288;              // 524288 f
    float* hbuf  = decp + 524288;              // 16384 f
    int*   sync  = (int*)(hbuf + 16384);       // 64 int ([0]=count,[32]=go)
    float* zbias = (float*)(sync + 64);        // 512 f
    unsigned short* U0 = (unsigned short*)(zbias + 512);
    unsigned short* inp_h   = U0;               // 524288
    unsigned short* inp_l   = U0 + 524288;      // 524288
    unsigned short* Wih_h   = U0 + 1048576;     // 786432
    unsigned short* Wih_l   = U0 + 1835008;     // 786432
    unsigned short* Wattn_h = U0 + 2621440;     // 524288
    unsigned short* Wattn_l = U0 + 3145728;     // 524288
    unsigned short* Wden_h  = U0 + 3670016;     // 524288
    unsigned short* Wden_l  = U0 + 4194304;     // 524288
    unsigned short* enc_h   = U0 + 4718592;     // 524288
    unsigned short* enc_l   = U0 + 5242880;     // 524288
    unsigned short* Wout_bf = U0 + 5767168;     // 16384000
    // cat hi/lo alias the inp/Wih splits (dead after x_proj):
    unsigned short* cath = U0;                  // 1048576 (1024x1024)
    unsigned short* catl = U0 + 1048576;        // 1048576
    // dense_bf aliases encp (dead after attn):
    unsigned short* dense_bf = (unsigned short*)encp;   // 524288

    // 1. zero hbuf + sync + zbias (contiguous: 16384 + 64 + 512 floats worth)
    zero_kernel<<<(16384 + 64 + 512 + 255) / 256, 256, 0, stream>>>(hbuf, 16384 + 64 + 512);
    // 2. converts / splits
    f32_to_bf16_kernel<<<4096, 256, 0, stream>>>(W_out, Wout_bf, Vdim * Hdim);
    split_bf16_kernel<<<256, 256, 0, stream>>>(input_seqs, inp_h, inp_l, BT * Hdim);
    split_bf16_kernel<<<256, 256, 0, stream>>>(W_ih, Wih_h, Wih_l, 1536 * Hdim);
    split_bf16_kernel<<<256, 256, 0, stream>>>(W_attn, Wattn_h, Wattn_l, Hdim * 1024);
    split_bf16_kernel<<<256, 256, 0, stream>>>(W_dense, Wden_h, Wden_l, Hdim * 1024);
    split_bf16_kernel<<<256, 256, 0, stream>>>(enc_out, enc_h, enc_l, BT * Hdim);

    // 3. x_proj = input_seqs @ W_ih^T + b_ih   (1024 x 1536, K=512)
    gemm_split<<<dim3(1536 / 128, BT / 128), 256, 0, stream>>>(
        inp_h, inp_l, Hdim, Wih_h, Wih_l, Hdim, b_ih, xp, nullptr, 1536, Hdim, 0);

    // 4. enc_p = enc @ We^T  (We = W_attn[:, :512], ldb=1024), no bias
    gemm_split<<<dim3(Hdim / 128, BT / 128), 256, 0, stream>>>(
        enc_h, enc_l, Hdim, Wattn_h, Wattn_l, 1024, zbias, encp, nullptr, Hdim, Hdim, 0);

    // 5. GRU (persistent; writes cat cols [0,512) as hi/lo bf16, h_last)
    gru_persistent<<<GRU_BLOCKS, 256, 0, stream>>>(
        xp, W_hh, b_hh, input_len, hbuf, sync, cath, catl, h_last);

    // 6. dec_p = dec_out @ Wd^T (A = cat[:, :512] hi/lo, lda=1024), no bias
    gemm_split<<<dim3(Hdim / 128, BT / 128), 256, 0, stream>>>(
        cath, catl, 1024, Wattn_h + 512, Wattn_l + 512, 1024, zbias, decp, nullptr, Hdim, Hdim, 0);

    // 7. attention -> cat cols [512,1024) hi/lo bf16
    attn_kernel<<<BT, 256, 0, stream>>>(encp, decp, enc_out, b_attn, v_w, v_b,
                                        enc_len, input_len, cath, catl);

    // 8. dense = tanh(cat @ W_dense^T + b_dense) -> bf16 directly (K=1024)
    gemm_split<<<dim3(Hdim / 128, BT / 128), 256, 0, stream>>>(
        cath, catl, 1024, Wden_h, Wden_l, 1024, b_dense, nullptr, dense_bf, Hdim, 1024, 1);

    // 9. logits = dense @ W_out^T + b_out  (1024 x 32000, K=512)
    gemm_logits<<<dim3(Vdim / 128, BT / 128), 256, 0, stream>>>(
        dense_bf, Wout_bf, b_out, logits);
}